// Round 1
// baseline (97.292 us; speedup 1.0000x reference)
//
#include <hip/hip_runtime.h>
#include <math.h>

#define Bn  16
#define Ln  256
#define Wn  4
#define Hn  128
#define Nn  259          // L + W - 1
#define EPSF 1e-6f

// LDS row stride (floats): 132 = 128 + 4 keeps float4 alignment (528 B, 16B-aligned)
// and maps row r to bank offset 4r -> at most 2-way conflicts (free on gfx950).
#define STR 132

__device__ __forceinline__ void acc_sq(const float4 a, const float4 b, float& s) {
    float d;
    d = a.x - b.x; s += d * d;
    d = a.y - b.y; s += d * d;
    d = a.z - b.z; s += d * d;
    d = a.w - b.w; s += d * d;
}

// Block: 256 threads. blockIdx.x = i-tile (17 tiles of 16), blockIdx.y = batch.
// Computes att[b, i0..i0+15, 0..N) ; accumulates
//   x2a[b,i] = sum_j att  (complete within block -> plain store)
//   x1a[b,j] = sum_i att  (partial per block -> atomicAdd, 17 contributors)
__global__ __launch_bounds__(256) void att_sums(const float* __restrict__ x1,
                                                const float* __restrict__ x2,
                                                float* __restrict__ x1a,
                                                float* __restrict__ x2a) {
    __shared__ float x2t[16 * STR];
    __shared__ float x1t[64 * STR];
    __shared__ float colpart[16 * 68];   // [ti][joff], stride 68 -> conflict-free stores

    const int it  = blockIdx.x;
    const int b   = blockIdx.y;
    const int i0  = it * 16;
    const int tid = threadIdx.x;
    const int ti  = tid >> 4;    // 0..15 : i offset (16 contiguous lanes share ti)
    const int tjg = tid & 15;    // 0..15 : j group

    const float* __restrict__ x1b = x1 + (size_t)b * Nn * Hn;
    const float* __restrict__ x2b = x2 + (size_t)b * Nn * Hn;

    // stage 16 x2 rows (zeros past N)
    for (int idx = tid; idx < 16 * 32; idx += 256) {
        const int r = idx >> 5, c4 = idx & 31;
        float4 v = make_float4(0.f, 0.f, 0.f, 0.f);
        if (i0 + r < Nn) v = ((const float4*)(x2b + (i0 + r) * Hn))[c4];
        *((float4*)&x2t[r * STR + c4 * 4]) = v;
    }

    const int  i      = i0 + ti;
    const bool ivalid = (i < Nn);
    float rowacc = 0.f;

    for (int j0 = 0; j0 < Nn; j0 += 64) {
        __syncthreads();   // prior tile fully consumed (incl. colpart reducers)
        // stage 64 x1 rows, coalesced: consecutive lanes -> consecutive float4
        for (int idx = tid; idx < 64 * 32; idx += 256) {
            const int r = idx >> 5, c4 = idx & 31;
            float4 v = make_float4(0.f, 0.f, 0.f, 0.f);
            if (j0 + r < Nn) v = ((const float4*)(x1b + (j0 + r) * Hn))[c4];
            *((float4*)&x1t[r * STR + c4 * 4]) = v;
        }
        __syncthreads();

        float s0 = 0.f, s1 = 0.f, s2 = 0.f, s3 = 0.f;
        #pragma unroll 8
        for (int h4 = 0; h4 < 32; ++h4) {
            const float4 a  = *((const float4*)&x2t[ti * STR + h4 * 4]);
            const float4 b0 = *((const float4*)&x1t[(tjg     ) * STR + h4 * 4]);
            const float4 b1 = *((const float4*)&x1t[(tjg + 16) * STR + h4 * 4]);
            const float4 b2 = *((const float4*)&x1t[(tjg + 32) * STR + h4 * 4]);
            const float4 b3 = *((const float4*)&x1t[(tjg + 48) * STR + h4 * 4]);
            acc_sq(a, b0, s0);
            acc_sq(a, b1, s1);
            acc_sq(a, b2, s2);
            acc_sq(a, b3, s3);
        }

        const bool jv0 = ivalid && (j0 + tjg      < Nn);
        const bool jv1 = ivalid && (j0 + tjg + 16 < Nn);
        const bool jv2 = ivalid && (j0 + tjg + 32 < Nn);
        const bool jv3 = ivalid && (j0 + tjg + 48 < Nn);
        const float att0 = jv0 ? 1.f / (sqrtf(s0 + EPSF) + 1.f) : 0.f;
        const float att1 = jv1 ? 1.f / (sqrtf(s1 + EPSF) + 1.f) : 0.f;
        const float att2 = jv2 ? 1.f / (sqrtf(s2 + EPSF) + 1.f) : 0.f;
        const float att3 = jv3 ? 1.f / (sqrtf(s3 + EPSF) + 1.f) : 0.f;

        rowacc += att0 + att1 + att2 + att3;

        colpart[ti * 68 + tjg     ] = att0;
        colpart[ti * 68 + tjg + 16] = att1;
        colpart[ti * 68 + tjg + 32] = att2;
        colpart[ti * 68 + tjg + 48] = att3;
        __syncthreads();

        if (tid < 64) {
            const int j = j0 + tid;
            if (j < Nn) {
                float cs = 0.f;
                #pragma unroll
                for (int t = 0; t < 16; ++t) cs += colpart[t * 68 + tid];
                atomicAdd(&x1a[b * Nn + j], cs);
            }
        }
    }

    // row sums: 16 contiguous lanes share one i -> shuffle reduce within groups of 16
    #pragma unroll
    for (int off = 8; off; off >>= 1) rowacc += __shfl_down(rowacc, off, 16);
    if (tjg == 0 && ivalid) x2a[b * Nn + i] = rowacc;
}

// out1[b,l,h] = sum_{k<4} x1[b,l+k,h] * x1a[b,l+k] ; same for out2 with x2/x2a.
// One float4 per thread; first half of grid -> out1, second -> out2.
__global__ __launch_bounds__(256) void wp_kernel(const float* __restrict__ x1,
                                                 const float* __restrict__ x2,
                                                 const float* __restrict__ x1a,
                                                 const float* __restrict__ x2a,
                                                 float* __restrict__ out) {
    const int PER = Bn * Ln * Hn / 4;    // 131072 float4 per output
    int g = blockIdx.x * 256 + threadIdx.x;
    const float* x; const float* a; float4* o; int e;
    if (g < PER) { x = x1; a = x1a; o = (float4*)out;       e = g; }
    else         { x = x2; a = x2a; o = (float4*)out + PER; e = g - PER; }

    const int b   = e >> 13;       // / (L*H/4) = 8192
    const int rem = e & 8191;
    const int l   = rem >> 5;      // / (H/4)
    const int h4  = rem & 31;

    const float4* xb = (const float4*)(x + (size_t)b * Nn * Hn);
    float4 acc = make_float4(0.f, 0.f, 0.f, 0.f);
    #pragma unroll
    for (int k = 0; k < Wn; ++k) {
        const float  av = a[b * Nn + l + k];
        const float4 xv = xb[(l + k) * (Hn / 4) + h4];
        acc.x += av * xv.x;
        acc.y += av * xv.y;
        acc.z += av * xv.z;
        acc.w += av * xv.w;
    }
    o[e] = acc;
}

extern "C" void kernel_launch(void* const* d_in, const int* in_sizes, int n_in,
                              void* d_out, int out_size, void* d_ws, size_t ws_size,
                              hipStream_t stream) {
    const float* x1 = (const float*)d_in[0];
    const float* x2 = (const float*)d_in[1];
    float* x1a = (float*)d_ws;              // B*N floats, atomic-accumulated
    float* x2a = x1a + Bn * Nn;             // B*N floats, plain stores

    hipMemsetAsync(d_ws, 0, (size_t)Bn * Nn * sizeof(float), stream);

    dim3 gridA(17, Bn);                     // ceil(259/16) i-tiles x batches
    att_sums<<<gridA, 256, 0, stream>>>(x1, x2, x1a, x2a);

    const int total_f4 = 2 * Bn * Ln * Hn / 4;   // 262144
    wp_kernel<<<total_f4 / 256, 256, 0, stream>>>(x1, x2, x1a, x2a, (float*)d_out);
}

// Round 2
// 77.561 us; speedup vs baseline: 1.2544x; 1.2544x over previous
//
#include <hip/hip_runtime.h>
#include <math.h>

#define Bn  16
#define Ln  256
#define Wn  4
#define Hn  128
#define Nn  259          // L + W - 1
#define EPSF 1e-6f
#define NB  (Bn * Nn)    // 4144

// LDS row stride (floats): 132 -> 528 B/row, 16B-aligned, banks rotate by 4/row.
#define STR 132

// ws layout (floats): x1a[NB] | x2a[NB] | n1[NB] | n2[NB]

// One wave per row: compute ||row||^2, zero the matching accumulator slot.
__global__ __launch_bounds__(256) void prep(const float* __restrict__ x1,
                                            const float* __restrict__ x2,
                                            float* __restrict__ ws) {
    const int wid  = (blockIdx.x * 256 + threadIdx.x) >> 6;   // global wave id
    const int lane = threadIdx.x & 63;
    if (wid >= 2 * NB) return;                                // wave-uniform
    const float* x = (wid < NB) ? x1 : x2;
    const int    r = (wid < NB) ? wid : wid - NB;
    const float2 v = ((const float2*)(x + (size_t)r * Hn))[lane];
    float s = v.x * v.x + v.y * v.y;
    #pragma unroll
    for (int off = 32; off; off >>= 1) s += __shfl_down(s, off);
    if (lane == 0) {
        ws[wid]          = 0.f;   // zero x1a (wid<NB) / x2a (wid>=NB)
        ws[2 * NB + wid] = s;     // n1 / n2
    }
}

// Block computes att tile [32 i x 64 j] for one batch via dot products + norms.
// Thread (ti2 = tid>>4, tjg = tid&15) owns 2i x 4j accumulators.
//   x2a[b,i] += sum_j att   (atomic, 5 j-tile contributors)
//   x1a[b,j] += sum_i att   (atomic, 9 i-tile contributors)
__global__ __launch_bounds__(256, 3) void att_sums(const float* __restrict__ x1,
                                                   const float* __restrict__ x2,
                                                   float* __restrict__ ws) {
    __shared__ float x2t[32 * STR];
    __shared__ float x1t[64 * STR];
    __shared__ float nrm[96];            // n2 rows [0,32) | n1 rows [32,96)

    float*       x1a = ws;
    float*       x2a = ws + NB;
    const float* n1g = ws + 2 * NB;
    const float* n2g = ws + 3 * NB;

    const int b   = blockIdx.z;
    const int i0  = blockIdx.x * 32;
    const int j0  = blockIdx.y * 64;
    const int tid = threadIdx.x;
    const int ti2 = tid >> 4;            // 0..15
    const int tjg = tid & 15;            // 0..15

    const float* __restrict__ x1b = x1 + (size_t)b * Nn * Hn;
    const float* __restrict__ x2b = x2 + (size_t)b * Nn * Hn;

    for (int idx = tid; idx < 32 * 32; idx += 256) {
        const int r = idx >> 5, c = idx & 31;
        float4 v = make_float4(0.f, 0.f, 0.f, 0.f);
        if (i0 + r < Nn) v = ((const float4*)(x2b + (i0 + r) * Hn))[c];
        *((float4*)&x2t[r * STR + c * 4]) = v;
    }
    for (int idx = tid; idx < 64 * 32; idx += 256) {
        const int r = idx >> 5, c = idx & 31;
        float4 v = make_float4(0.f, 0.f, 0.f, 0.f);
        if (j0 + r < Nn) v = ((const float4*)(x1b + (j0 + r) * Hn))[c];
        *((float4*)&x1t[r * STR + c * 4]) = v;
    }
    if (tid < 32)       nrm[tid]      = (i0 + tid < Nn)        ? n2g[b * Nn + i0 + tid]        : 0.f;
    else if (tid < 96)  nrm[tid]      = (j0 + (tid - 32) < Nn) ? n1g[b * Nn + j0 + (tid - 32)] : 0.f;
    __syncthreads();

    float d00 = 0.f, d01 = 0.f, d02 = 0.f, d03 = 0.f;
    float d10 = 0.f, d11 = 0.f, d12 = 0.f, d13 = 0.f;
    const float* arow0 = &x2t[(ti2 * 2    ) * STR];
    const float* arow1 = &x2t[(ti2 * 2 + 1) * STR];
    const float* brow0 = &x1t[(tjg       ) * STR];
    const float* brow1 = &x1t[(tjg + 16  ) * STR];
    const float* brow2 = &x1t[(tjg + 32  ) * STR];
    const float* brow3 = &x1t[(tjg + 48  ) * STR];

    #pragma unroll 4
    for (int h4 = 0; h4 < 32; ++h4) {
        const float4 a0 = *((const float4*)&arow0[h4 * 4]);
        const float4 a1 = *((const float4*)&arow1[h4 * 4]);
        const float4 v0 = *((const float4*)&brow0[h4 * 4]);
        const float4 v1 = *((const float4*)&brow1[h4 * 4]);
        const float4 v2 = *((const float4*)&brow2[h4 * 4]);
        const float4 v3 = *((const float4*)&brow3[h4 * 4]);
        d00 += a0.x * v0.x + a0.y * v0.y + a0.z * v0.z + a0.w * v0.w;
        d01 += a0.x * v1.x + a0.y * v1.y + a0.z * v1.z + a0.w * v1.w;
        d02 += a0.x * v2.x + a0.y * v2.y + a0.z * v2.z + a0.w * v2.w;
        d03 += a0.x * v3.x + a0.y * v3.y + a0.z * v3.z + a0.w * v3.w;
        d10 += a1.x * v0.x + a1.y * v0.y + a1.z * v0.z + a1.w * v0.w;
        d11 += a1.x * v1.x + a1.y * v1.y + a1.z * v1.z + a1.w * v1.w;
        d12 += a1.x * v2.x + a1.y * v2.y + a1.z * v2.z + a1.w * v2.w;
        d13 += a1.x * v3.x + a1.y * v3.y + a1.z * v3.z + a1.w * v3.w;
    }

    const int  ia = i0 + ti2 * 2, ib = ia + 1;
    const bool iva = (ia < Nn), ivb = (ib < Nn);
    const float n2a = nrm[ti2 * 2], n2b = nrm[ti2 * 2 + 1];

    float att0[4], att1[4];
    #pragma unroll
    for (int k = 0; k < 4; ++k) {
        const int   j   = j0 + tjg + 16 * k;
        const bool  jv  = (j < Nn);
        const float n1v = nrm[32 + tjg + 16 * k];
        const float dk0 = (k == 0) ? d00 : (k == 1) ? d01 : (k == 2) ? d02 : d03;
        const float dk1 = (k == 0) ? d10 : (k == 1) ? d11 : (k == 2) ? d12 : d13;
        const float e0  = n2a + n1v - 2.f * dk0 + EPSF;
        const float e1  = n2b + n1v - 2.f * dk1 + EPSF;
        att0[k] = (iva && jv) ? 1.f / (sqrtf(e0) + 1.f) : 0.f;
        att1[k] = (ivb && jv) ? 1.f / (sqrtf(e1) + 1.f) : 0.f;
    }

    // row sums over this block's 64 j: reduce across the 16 contiguous lanes
    float ra = att0[0] + att0[1] + att0[2] + att0[3];
    float rb = att1[0] + att1[1] + att1[2] + att1[3];
    #pragma unroll
    for (int off = 8; off; off >>= 1) {
        ra += __shfl_down(ra, off, 16);
        rb += __shfl_down(rb, off, 16);
    }

    // column partials: overlay on x2t (all compute reads done after this barrier)
    __syncthreads();
    float* colpart = x2t;                // 16 x 68
    #pragma unroll
    for (int k = 0; k < 4; ++k)
        colpart[ti2 * 68 + tjg + 16 * k] = att0[k] + att1[k];

    if (tjg == 0) {
        if (iva) atomicAdd(&x2a[b * Nn + ia], ra);
        if (ivb) atomicAdd(&x2a[b * Nn + ib], rb);
    }
    __syncthreads();
    if (tid < 64) {
        const int j = j0 + tid;
        if (j < Nn) {
            float cs = 0.f;
            #pragma unroll
            for (int t = 0; t < 16; ++t) cs += colpart[t * 68 + tid];
            atomicAdd(&x1a[b * Nn + j], cs);
        }
    }
}

// out[b,l,h] = sum_{k<4} x[b,l+k,h] * a[b,l+k]; first half of grid -> out1.
__global__ __launch_bounds__(256) void wp_kernel(const float* __restrict__ x1,
                                                 const float* __restrict__ x2,
                                                 const float* __restrict__ ws,
                                                 float* __restrict__ out) {
    const int PER = Bn * Ln * Hn / 4;    // 131072 float4 per output
    int g = blockIdx.x * 256 + threadIdx.x;
    const float* x; const float* a; float4* o; int e;
    if (g < PER) { x = x1; a = ws;      o = (float4*)out;       e = g; }
    else         { x = x2; a = ws + NB; o = (float4*)out + PER; e = g - PER; }

    const int b   = e >> 13;
    const int rem = e & 8191;
    const int l   = rem >> 5;
    const int h4  = rem & 31;

    const float4* xb = (const float4*)(x + (size_t)b * Nn * Hn);
    float4 acc = make_float4(0.f, 0.f, 0.f, 0.f);
    #pragma unroll
    for (int k = 0; k < Wn; ++k) {
        const float  av = a[b * Nn + l + k];
        const float4 xv = xb[(l + k) * (Hn / 4) + h4];
        acc.x += av * xv.x;
        acc.y += av * xv.y;
        acc.z += av * xv.z;
        acc.w += av * xv.w;
    }
    o[e] = acc;
}

extern "C" void kernel_launch(void* const* d_in, const int* in_sizes, int n_in,
                              void* d_out, int out_size, void* d_ws, size_t ws_size,
                              hipStream_t stream) {
    const float* x1 = (const float*)d_in[0];
    const float* x2 = (const float*)d_in[1];
    float* ws = (float*)d_ws;

    prep<<<(2 * NB + 3) / 4, 256, 0, stream>>>(x1, x2, ws);   // 2072 blocks

    dim3 gridA(9, 5, Bn);                 // ceil(259/32) x ceil(259/64) x B
    att_sums<<<gridA, 256, 0, stream>>>(x1, x2, ws);

    const int total_f4 = 2 * Bn * Ln * Hn / 4;   // 262144
    wp_kernel<<<total_f4 / 256, 256, 0, stream>>>(x1, x2, ws, (float*)d_out);
}

// Round 3
// 70.537 us; speedup vs baseline: 1.3793x; 1.0996x over previous
//
#include <hip/hip_runtime.h>
#include <hip/hip_bf16.h>
#include <math.h>

#define Bn  16
#define Ln  256
#define Wn  4
#define Hn  128
#define Nn  259          // L + W - 1
#define EPSF 1e-6f
#define NB  (Bn * Nn)    // 4144

typedef float f32x4 __attribute__((ext_vector_type(4)));
typedef short s16x8 __attribute__((ext_vector_type(8)));

// ws layout: x1a[NB] | x2a[NB] | n1[NB] | n2[NB]  (floats)
//            xb1[NB*Hn] | xb2[NB*Hn]              (bf16 as ushort)
// 4*NB floats = 66304 B (16B aligned); xb rows are 256 B.

// One wave per row: bf16-convert the row, compute ||row_bf16||^2, zero the
// matching accumulator slot. Replaces memset + gives MFMA-ready operands.
__global__ __launch_bounds__(256) void prep(const float* __restrict__ x1,
                                            const float* __restrict__ x2,
                                            float* __restrict__ ws) {
    const int wid  = (blockIdx.x * 256 + threadIdx.x) >> 6;
    const int lane = threadIdx.x & 63;
    if (wid >= 2 * NB) return;                       // wave-uniform
    const bool one = (wid < NB);
    const float* x = one ? x1 : x2;
    const int    r = one ? wid : wid - NB;
    const float2 v = ((const float2*)(x + (size_t)r * Hn))[lane];
    union { __hip_bfloat16 h; unsigned short u; } c0, c1;
    c0.h = __float2bfloat16(v.x);
    c1.h = __float2bfloat16(v.y);
    unsigned short* xb = (unsigned short*)(ws + 4 * NB) + (one ? 0 : (size_t)NB * Hn);
    ((unsigned int*)(xb + (size_t)r * Hn))[lane] =
        (unsigned int)c0.u | ((unsigned int)c1.u << 16);
    const float a0 = __bfloat162float(c0.h), a1 = __bfloat162float(c1.h);
    float s = a0 * a0 + a1 * a1;
    #pragma unroll
    for (int off = 32; off; off >>= 1) s += __shfl_down(s, off);
    if (lane == 0) {
        ws[wid]          = 0.f;   // zero x1a / x2a
        ws[2 * NB + wid] = s;     // n1 / n2 (from bf16-rounded values)
    }
}

// Block: 64i x 64j att tile for one batch via bf16 MFMA 16x16x32.
// Wave w owns i-rows [i0+16w, i0+16w+16), all 64 j.
// A-frag (x2 rows): lane holds A[m=lane&15][k=(lane>>4)*8 + 0..7]  (m120)
// C/D: col = lane&15, row = (lane>>4)*4 + reg                      (m89/m91)
__global__ __launch_bounds__(256) void att_mfma(float* __restrict__ ws) {
    __shared__ unsigned short As[64 * 136];   // x2 tile; stride 136 (272 B) -> 2-way banks (free)
    __shared__ unsigned short Bs[64 * 136];   // x1 tile
    __shared__ float n2s[64], n1s[64];

    float*       x1a = ws;
    float*       x2a = ws + NB;
    const float* n1g = ws + 2 * NB;
    const float* n2g = ws + 3 * NB;
    const unsigned short* xb1 = (const unsigned short*)(ws + 4 * NB);
    const unsigned short* xb2 = xb1 + (size_t)NB * Hn;

    const int i0 = blockIdx.x * 64, j0 = blockIdx.y * 64, b = blockIdx.z;
    const int tid = threadIdx.x;

    // stage both tiles: 64 rows x 256 B each, 16 B per thread per step
    for (int idx = tid; idx < 1024; idx += 256) {
        const int r = idx >> 4, c = idx & 15;
        uint4 va = make_uint4(0, 0, 0, 0), vb = va;
        if (i0 + r < Nn) va = ((const uint4*)(xb2 + (size_t)(b * Nn + i0 + r) * Hn))[c];
        if (j0 + r < Nn) vb = ((const uint4*)(xb1 + (size_t)(b * Nn + j0 + r) * Hn))[c];
        *((uint4*)&As[r * 136 + c * 8]) = va;
        *((uint4*)&Bs[r * 136 + c * 8]) = vb;
    }
    if (tid < 64)       n2s[tid]      = (i0 + tid < Nn)        ? n2g[b * Nn + i0 + tid]        : 0.f;
    else if (tid < 128) n1s[tid - 64] = (j0 + (tid - 64) < Nn) ? n1g[b * Nn + j0 + (tid - 64)] : 0.f;
    __syncthreads();

    const int w = tid >> 6, lane = tid & 63;
    const int rsel = lane & 15, q = lane >> 4;

    f32x4 acc[4] = {{0,0,0,0}, {0,0,0,0}, {0,0,0,0}, {0,0,0,0}};
    const unsigned short* arow = &As[(w * 16 + rsel) * 136 + q * 8];
    const unsigned short* brow = &Bs[rsel * 136 + q * 8];
    #pragma unroll
    for (int s = 0; s < 4; ++s) {               // K-steps of 32
        const s16x8 af = *((const s16x8*)(arow + s * 32));
        #pragma unroll
        for (int t = 0; t < 4; ++t) {           // j-tiles of 16
            const s16x8 bf = *((const s16x8*)(brow + t * 16 * 136 + s * 32));
            acc[t] = __builtin_amdgcn_mfma_f32_16x16x32_bf16(af, bf, acc[t], 0, 0, 0);
        }
    }

    // epilogue: att = 1/(sqrt(n2+n1-2*dot+eps)+1), masked to valid (i,j)
    float rowacc[4] = {0.f, 0.f, 0.f, 0.f};
    #pragma unroll
    for (int t = 0; t < 4; ++t) {
        const int   j   = j0 + t * 16 + rsel;       // col = lane&15
        const bool  jv  = (j < Nn);
        const float n1v = n1s[t * 16 + rsel];
        float cp = 0.f;
        #pragma unroll
        for (int reg = 0; reg < 4; ++reg) {
            const int   i   = i0 + w * 16 + q * 4 + reg;   // row = q*4+reg
            const float e   = fmaf(-2.f, acc[t][reg], n2s[w * 16 + q * 4 + reg] + n1v + EPSF);
            const float att = ((i < Nn) && jv) ? 1.f / (sqrtf(e) + 1.f) : 0.f;
            rowacc[reg] += att;
            cp          += att;
        }
        // column sum over this wave's 16 rows: reduce across q (lane bits 4-5)
        cp += __shfl_xor(cp, 16);
        cp += __shfl_xor(cp, 32);
        if (q == 0 && jv) atomicAdd(&x1a[b * Nn + j], cp);
    }
    // row sums over 64 j: reduce across the 16 col-lanes
    #pragma unroll
    for (int reg = 0; reg < 4; ++reg) {
        float rs = rowacc[reg];
        #pragma unroll
        for (int off = 8; off; off >>= 1) rs += __shfl_down(rs, off, 16);
        const int i = i0 + w * 16 + q * 4 + reg;
        if (rsel == 0 && i < Nn) atomicAdd(&x2a[b * Nn + i], rs);
    }
}

// out[b,l,h] = sum_{k<4} x[b,l+k,h] * a[b,l+k]; first half of grid -> out1.
__global__ __launch_bounds__(256) void wp_kernel(const float* __restrict__ x1,
                                                 const float* __restrict__ x2,
                                                 const float* __restrict__ ws,
                                                 float* __restrict__ out) {
    const int PER = Bn * Ln * Hn / 4;    // 131072 float4 per output
    int g = blockIdx.x * 256 + threadIdx.x;
    const float* x; const float* a; float4* o; int e;
    if (g < PER) { x = x1; a = ws;      o = (float4*)out;       e = g; }
    else         { x = x2; a = ws + NB; o = (float4*)out + PER; e = g - PER; }

    const int b   = e >> 13;
    const int rem = e & 8191;
    const int l   = rem >> 5;
    const int h4  = rem & 31;

    const float4* xb = (const float4*)(x + (size_t)b * Nn * Hn);
    float4 acc = make_float4(0.f, 0.f, 0.f, 0.f);
    #pragma unroll
    for (int k = 0; k < Wn; ++k) {
        const float  av = a[b * Nn + l + k];
        const float4 xv = xb[(l + k) * (Hn / 4) + h4];
        acc.x += av * xv.x;
        acc.y += av * xv.y;
        acc.z += av * xv.z;
        acc.w += av * xv.w;
    }
    o[e] = acc;
}

extern "C" void kernel_launch(void* const* d_in, const int* in_sizes, int n_in,
                              void* d_out, int out_size, void* d_ws, size_t ws_size,
                              hipStream_t stream) {
    const float* x1 = (const float*)d_in[0];
    const float* x2 = (const float*)d_in[1];
    float* ws = (float*)d_ws;

    prep<<<(2 * NB + 3) / 4, 256, 0, stream>>>(x1, x2, ws);   // 2072 blocks

    dim3 gridA(5, 5, Bn);                 // 64x64 tiles over 259x259, 16 batches
    att_mfma<<<gridA, 256, 0, stream>>>(ws);

    const int total_f4 = 2 * Bn * Ln * Hn / 4;   // 262144
    wp_kernel<<<total_f4 / 256, 256, 0, stream>>>(x1, x2, ws, (float*)d_out);
}